// Round 3
// baseline (145.897 us; speedup 1.0000x reference)
//
#include <hip/hip_runtime.h>

// ---------------- workspace layout (bytes) ----------------
#define WS_SACC   0        // f32[20]: S1[c]=0..9, S2[c]=10..19
#define WS_DONE1  128      // i32 completion counter for k_rows
#define WS_DONE2  132      // i32 completion counter for k_main
#define WS_HIST   160      // i32[10] class counts (== counts)
#define WS_INVCNT 320      // f32[16]
#define WS_INVWN  384      // f32[16]
#define WS_TCLS   448      // i32[48]
#define WS_TVCNT  640      // i32[48]
#define WS_NTILES 832      // i32
#define WS_PERM   1024     // i32[5376] (42 tiles * 128)
#define WS_SQBF   23040    // f32[4096]
#define WS_PROJ   39424    // f32[4096*10]
#define WS_PREDBF 203264   // bf16[4096*128] = 1 MB

#define NCLS 10
#define NROW 4096
#define DDIM 128
#define MAXTILES 42

typedef __attribute__((ext_vector_type(8))) short short8;
typedef __attribute__((ext_vector_type(4))) float f32x4;

__device__ __forceinline__ unsigned short f2bf(float x) {
  unsigned int u = __float_as_uint(x);
  u += 0x7FFFu + ((u >> 16) & 1u);   // round-nearest-even
  return (unsigned short)(u >> 16);
}
__device__ __forceinline__ float bf2f(unsigned short b) {
  return __uint_as_float(((unsigned int)b) << 16);
}

// ---------------- K1: per-row bf16/sumsq/proj + hist; last block builds perm ----
// 128 blocks x 256 thr; 32 rows/block, 8 threads/row; W in LDS.
__global__ void __launch_bounds__(256)
k_rows(const float* __restrict__ pred, const float* __restrict__ W,
       const int* __restrict__ tgt, char* __restrict__ ws) {
  __shared__ float Wl[NCLS * DDIM];
  __shared__ int lh[NCLS];
  __shared__ int lastflag;
  int t = threadIdx.x;
  if (t < NCLS) lh[t] = 0;
  for (int s = t; s < NCLS * DDIM; s += 256) Wl[s] = W[s];
  __syncthreads();

  int row  = blockIdx.x * 32 + (t >> 3);
  int part = t & 7;
  const float4* p4 = (const float4*)(pred + row * DDIM + part * 16);
  unsigned short* pb = ((unsigned short*)(ws + WS_PREDBF)) + row * DDIM + part * 16;

  float4 v[4];
  float ss = 0.f;
#pragma unroll
  for (int ch = 0; ch < 4; ch++) {
    v[ch] = p4[ch];
    unsigned short b0 = f2bf(v[ch].x), b1 = f2bf(v[ch].y),
                   b2 = f2bf(v[ch].z), b3 = f2bf(v[ch].w);
    float r0 = bf2f(b0), r1 = bf2f(b1), r2 = bf2f(b2), r3 = bf2f(b3);
    ss = fmaf(r0, r0, ss); ss = fmaf(r1, r1, ss);
    ss = fmaf(r2, r2, ss); ss = fmaf(r3, r3, ss);
    ushort4 u; u.x = b0; u.y = b1; u.z = b2; u.w = b3;
    *((ushort4*)(pb + ch * 4)) = u;
  }
  float acc[NCLS];
#pragma unroll
  for (int c = 0; c < NCLS; c++) acc[c] = 0.f;
#pragma unroll
  for (int c = 0; c < NCLS; c++) {
#pragma unroll
    for (int ch = 0; ch < 4; ch++) {
      float4 w = *(const float4*)&Wl[c * DDIM + part * 16 + ch * 4];
      acc[c] = fmaf(v[ch].x, w.x, acc[c]);
      acc[c] = fmaf(v[ch].y, w.y, acc[c]);
      acc[c] = fmaf(v[ch].z, w.z, acc[c]);
      acc[c] = fmaf(v[ch].w, w.w, acc[c]);
    }
  }
#pragma unroll
  for (int m = 1; m <= 4; m <<= 1) {
    ss += __shfl_xor(ss, m, 64);
#pragma unroll
    for (int c = 0; c < NCLS; c++) acc[c] += __shfl_xor(acc[c], m, 64);
  }
  if (part == 0) {
    ((float*)(ws + WS_SQBF))[row] = ss;
    float* proj = (float*)(ws + WS_PROJ);
#pragma unroll
    for (int c = 0; c < NCLS; c++) proj[row * NCLS + c] = acc[c];
    atomicAdd(&lh[tgt[row]], 1);
  }
  __syncthreads();
  if (t < NCLS && lh[t] > 0) atomicAdd((int*)(ws + WS_HIST) + t, lh[t]);
  if (t == 0) {
    __threadfence();
    int old = __hip_atomic_fetch_add((int*)(ws + WS_DONE1), 1,
                                     __ATOMIC_ACQ_REL, __HIP_MEMORY_SCOPE_AGENT);
    lastflag = (old == (int)gridDim.x - 1);
  }
  __syncthreads();
  if (!lastflag) return;

  // ---- LAST BLOCK: counts -> invcnt, W-norms, tile table, perm scatter ----
  __shared__ int base_s[NCLS];
  __shared__ int cur[NCLS];
  if (t < NCLS) {
    int h = __hip_atomic_load((int*)(ws + WS_HIST) + t,
                              __ATOMIC_ACQUIRE, __HIP_MEMORY_SCOPE_AGENT);
    lh[t] = h;
    ((float*)(ws + WS_INVCNT))[t] = 1.0f / (float)max(h, 1);
    cur[t] = 0;
  }
  if (t < 160) {                      // W row norms: 16 lanes/class
    int c = t >> 4, ln = t & 15;
    float sw = 0.f;
#pragma unroll
    for (int k = 0; k < 8; k++) { float w = Wl[c * DDIM + ln * 8 + k]; sw = fmaf(w, w, sw); }
    sw += __shfl_xor(sw, 1, 64);
    sw += __shfl_xor(sw, 2, 64);
    sw += __shfl_xor(sw, 4, 64);
    sw += __shfl_xor(sw, 8, 64);
    if (ln == 0) ((float*)(ws + WS_INVWN))[c] = 1.0f / fmaxf(sqrtf(sw), 1e-8f);
  }
  __syncthreads();
  if (t == 0) {
    int nb = 0;
    int* tcls = (int*)(ws + WS_TCLS);
    int* tvc  = (int*)(ws + WS_TVCNT);
    for (int c = 0; c < NCLS; c++) {
      base_s[c] = nb * 128;
      int h = lh[c];
      int tiles = (h + 127) >> 7;
      for (int i = 0; i < tiles; i++) {
        tcls[nb + i] = c;
        tvc[nb + i]  = min(128, h - i * 128);
      }
      nb += tiles;
    }
    *((int*)(ws + WS_NTILES)) = nb;
  }
  __syncthreads();
  int* perm = (int*)(ws + WS_PERM);
  for (int s = t; s < MAXTILES * 128; s += 256) perm[s] = 0;  // pads -> safe row 0
  __syncthreads();
  for (int j = t; j < NROW; j += 256) {
    int c = tgt[j];
    int slot = base_s[c] + atomicAdd(&cur[c], 1);
    perm[slot] = j;
  }
}

// ---------------- K2: fused G-tile MFMA + pair epilogue; last block finalizes ----
// 128 thr (2 waves). Block: 128 perm A-rows (uniform class) x 128 natural B-rows.
// Wave w holds afrag for 64 A-rows in regs; streams 8 B-steps of 16 rows.
__global__ void __launch_bounds__(128)
k_main(const int* __restrict__ tgt, char* __restrict__ ws, float* __restrict__ out) {
  const int t = threadIdx.x;
  const int ntiles = *((const int*)(ws + WS_NTILES));
  const int ta = blockIdx.x >> 5;
  const int tb = blockIdx.x & 31;

  if (ta < ntiles) {
    const int cls  = ((const int*)(ws + WS_TCLS))[ta];
    const int vcnt = ((const int*)(ws + WS_TVCNT))[ta];
    const float invcnt_cls = ((const float*)(ws + WS_INVCNT))[cls];
    const float invwn_cls  = ((const float*)(ws + WS_INVWN))[cls];

    __shared__ __align__(16) float sqa_s[128];
    __shared__ __align__(16) float pa_s[128];
    __shared__ float sqb_s[128], pnb_s[128], wvb_s[128];
    __shared__ int   arow_s[128];
    __shared__ float red_s[2][2];

    const float* sqbf   = (const float*)(ws + WS_SQBF);
    const float* proj   = (const float*)(ws + WS_PROJ);
    const int*   perm   = (const int*)(ws + WS_PERM);
    const float* invcnt = (const float*)(ws + WS_INVCNT);
    const unsigned short* predbf = (const unsigned short*)(ws + WS_PREDBF);

    {
      int b = tb * 128 + t;
      int cb = tgt[b];
      sqb_s[t] = sqbf[b] + 1e-16f;                       // fold +1e-16
      pnb_s[t] = proj[b * NCLS + cls] * invwn_cls;
      wvb_s[t] = (cb != cls) ? invcnt[cb] * invcnt_cls : 0.0f;  // full pair weight
      int row = perm[ta * 128 + t];
      arow_s[t] = row;
      sqa_s[t] = (t < vcnt) ? sqbf[row] : __builtin_inff();     // pads: M -> 0
      pa_s[t]  = proj[row * NCLS + cls] * invwn_cls;
    }
    __syncthreads();

    const int lane = t & 63, w = t >> 6;
    const int l16 = lane & 15, quad = lane >> 4;

    // A fragments for this wave's 64 rows: A[m=l16][k=quad*8+j]
    short8 afrag[4][4];
    f32x4 sqa4[4], pa4[4];
#pragma unroll
    for (int fi = 0; fi < 4; fi++) {
      int ra = w * 64 + fi * 16 + l16;
      const unsigned short* ap = predbf + arow_s[ra] * DDIM + quad * 8;
#pragma unroll
      for (int kk = 0; kk < 4; kk++) afrag[fi][kk] = *(const short8*)(ap + kk * 32);
      int vi = w * 16 + fi * 4 + quad;          // C-layout: m = vi*4 + r
      sqa4[fi] = *(const f32x4*)(sqa_s + vi * 4);
      pa4[fi]  = *(const f32x4*)(pa_s + vi * 4);
    }

    float S1 = 0.f, S2 = 0.f;
    const unsigned short* bbase = predbf + (tb * 128 + l16) * DDIM + quad * 8;
    short8 bcur[4], bnxt[4];
#pragma unroll
    for (int kk = 0; kk < 4; kk++) bcur[kk] = *(const short8*)(bbase + kk * 32);

#pragma unroll 2
    for (int s = 0; s < 8; s++) {
      if (s < 7) {
        const unsigned short* bp = bbase + (s + 1) * 16 * DDIM;
#pragma unroll
        for (int kk = 0; kk < 4; kk++) bnxt[kk] = *(const short8*)(bp + kk * 32);
      }
      int bi = s * 16 + l16;
      float sqb = sqb_s[bi], pnb = pnb_s[bi], wg = wvb_s[bi];
#pragma unroll
      for (int fi = 0; fi < 4; fi++) {
        f32x4 acc = {0.f, 0.f, 0.f, 0.f};
#pragma unroll
        for (int kk = 0; kk < 4; kk++)
          acc = __builtin_amdgcn_mfma_f32_16x16x32_bf16(afrag[fi][kk], bcur[kk], acc, 0, 0, 0);
#pragma unroll
        for (int r = 0; r < 4; r++) {
          float d2 = fmaf(-2.0f, acc[r], sqa4[fi][r] + sqb);
          d2 = fmaxf(d2, 1e-16f);
          float rin = rsqrtf(d2);               // 1/dn (max with 1e-8 is a no-op)
          float M  = (pa4[fi][r] - pnb) * rin;
          float wM = wg * M;
          S1 += wM;
          S2 = fmaf(wM, M, S2);
        }
      }
#pragma unroll
      for (int kk = 0; kk < 4; kk++) bcur[kk] = bnxt[kk];
    }

#pragma unroll
    for (int off = 32; off > 0; off >>= 1) {
      S1 += __shfl_xor(S1, off, 64);
      S2 += __shfl_xor(S2, off, 64);
    }
    if (lane == 0) { red_s[w][0] = S1; red_s[w][1] = S2; }
    __syncthreads();
    if (t == 0) {
      float* Sacc = (float*)(ws + WS_SACC);
      atomicAdd(&Sacc[cls],      red_s[0][0] + red_s[1][0]);
      atomicAdd(&Sacc[10 + cls], red_s[0][1] + red_s[1][1]);
    }
  }

  // ---- completion counter; last block computes the two outputs ----
  if (t == 0) {
    __threadfence();
    int old = __hip_atomic_fetch_add((int*)(ws + WS_DONE2), 1,
                                     __ATOMIC_ACQ_REL, __HIP_MEMORY_SCOPE_AGENT);
    if (old == (int)gridDim.x - 1) {
      const int* hist = (const int*)(ws + WS_HIST);
      float* Sacc = (float*)(ws + WS_SACC);
      float exist = 0.f;
      for (int c = 0; c < NCLS; c++) if (hist[c] > 0) exist += 1.f;
      float em1 = exist - 1.0f;                 // S0 per class == exist-1 (exact)
      float l1 = 0.f, l2 = 0.f;
      for (int c = 0; c < NCLS; c++) {
        if (hist[c] <= 0) continue;
        float s1 = __hip_atomic_load(&Sacc[c],      __ATOMIC_ACQUIRE, __HIP_MEMORY_SCOPE_AGENT);
        float s2 = __hip_atomic_load(&Sacc[10 + c], __ATOMIC_ACQUIRE, __HIP_MEMORY_SCOPE_AGENT);
        l1 += (em1 - 2.f * s1 + s2) / em1;
        float mm = s1 / em1;
        float mv = s2 / em1 - mm * mm;          // (S2 - 2*mm*S1 + mm^2*S0)/em1, S0=em1
        l2 += fabsf(mv / mm);
      }
      out[0] = l1 / exist;
      out[1] = l2 / exist;
    }
  }
}

extern "C" void kernel_launch(void* const* d_in, const int* in_sizes, int n_in,
                              void* d_out, int out_size, void* d_ws, size_t ws_size,
                              hipStream_t stream) {
  const float* pred = (const float*)d_in[0];
  const int*   tgt  = (const int*)d_in[1];
  const float* W    = (const float*)d_in[2];
  float* out = (float*)d_out;
  char*  ws  = (char*)d_ws;

  hipMemsetAsync(ws, 0, 256, stream);   // zero SACC, DONE1, DONE2, HIST
  k_rows<<<NROW / 32, 256, 0, stream>>>(pred, W, tgt, ws);
  k_main<<<MAXTILES * 32, 128, 0, stream>>>(tgt, ws, out);
}

// Round 4
// 112.665 us; speedup vs baseline: 1.2950x; 1.2950x over previous
//
#include <hip/hip_runtime.h>

// ---------------- workspace layout (bytes) ----------------
#define WS_SACC   0        // f32[20]: S1[c]=0..9, S2[c]=10..19
#define WS_DONE   128      // i32 completion counter for k_main
#define WS_GCUR   192      // i32[10], stride 64B (atomic cursors == final counts)
#define WS_INVWN  896      // f32[10]
#define WS_PERM   1024     // i32[10*4096] fixed 4096-slot region per class (160 KB)
#define WS_SQBF   165888   // f32[4096]
#define WS_PROJ   182272   // f32[4096*10]
#define WS_PREDBF 346112   // bf16[4096*128] = 1 MB

#define NCLS 10
#define NROW 4096
#define DDIM 128
#define MAXT 42            // max total 128-row class tiles: 32 + 10
#define GRID_MAIN (MAXT * MAXT)

typedef __attribute__((ext_vector_type(8))) short short8;
typedef __attribute__((ext_vector_type(4))) float f32x4;

#define AS3(p) ((__attribute__((address_space(3))) void*)(p))
#define AS1(p) ((const __attribute__((address_space(1))) void*)(p))

__device__ __forceinline__ unsigned short f2bf(float x) {
  unsigned int u = __float_as_uint(x);
  u += 0x7FFFu + ((u >> 16) & 1u);   // round-nearest-even
  return (unsigned short)(u >> 16);
}
__device__ __forceinline__ float bf2f(unsigned short b) {
  return __uint_as_float(((unsigned int)b) << 16);
}

// ---------------- K1: bf16 convert, sumsq, proj, invwn, class-sorted perm ----
// 128 blocks x 256 thr; 32 rows/block, 8 threads/row; W in LDS. No fences.
__global__ void __launch_bounds__(256)
k_rows(const float* __restrict__ pred, const float* __restrict__ W,
       const int* __restrict__ tgt, char* __restrict__ ws) {
  __shared__ float Wl[NCLS * DDIM];
  __shared__ int lcnt[NCLS];
  __shared__ int gbase_s[NCLS];
  int t = threadIdx.x;
  if (t < NCLS) lcnt[t] = 0;
  for (int s = t; s < NCLS * DDIM; s += 256) Wl[s] = W[s];
  __syncthreads();

  // invwn (every block writes the same values; benign)
  if (t < 160) {
    int c = t >> 4, ln = t & 15;
    float sw = 0.f;
#pragma unroll
    for (int k = 0; k < 8; k++) { float w = Wl[c * DDIM + ln * 8 + k]; sw = fmaf(w, w, sw); }
    sw += __shfl_xor(sw, 1, 64);
    sw += __shfl_xor(sw, 2, 64);
    sw += __shfl_xor(sw, 4, 64);
    sw += __shfl_xor(sw, 8, 64);
    if (ln == 0) ((float*)(ws + WS_INVWN))[c] = 1.0f / fmaxf(sqrtf(sw), 1e-8f);
  }

  int row  = blockIdx.x * 32 + (t >> 3);
  int part = t & 7;
  const float4* p4 = (const float4*)(pred + row * DDIM + part * 16);
  unsigned short* pb = ((unsigned short*)(ws + WS_PREDBF)) + row * DDIM + part * 16;

  float4 v[4];
  float ss = 0.f;
#pragma unroll
  for (int ch = 0; ch < 4; ch++) {
    v[ch] = p4[ch];
    unsigned short b0 = f2bf(v[ch].x), b1 = f2bf(v[ch].y),
                   b2 = f2bf(v[ch].z), b3 = f2bf(v[ch].w);
    float r0 = bf2f(b0), r1 = bf2f(b1), r2 = bf2f(b2), r3 = bf2f(b3);
    ss = fmaf(r0, r0, ss); ss = fmaf(r1, r1, ss);
    ss = fmaf(r2, r2, ss); ss = fmaf(r3, r3, ss);
    ushort4 u; u.x = b0; u.y = b1; u.z = b2; u.w = b3;
    *((ushort4*)(pb + ch * 4)) = u;
  }
  float acc[NCLS];
#pragma unroll
  for (int c = 0; c < NCLS; c++) acc[c] = 0.f;
#pragma unroll
  for (int c = 0; c < NCLS; c++) {
#pragma unroll
    for (int ch = 0; ch < 4; ch++) {
      float4 w = *(const float4*)&Wl[c * DDIM + part * 16 + ch * 4];
      acc[c] = fmaf(v[ch].x, w.x, acc[c]);
      acc[c] = fmaf(v[ch].y, w.y, acc[c]);
      acc[c] = fmaf(v[ch].z, w.z, acc[c]);
      acc[c] = fmaf(v[ch].w, w.w, acc[c]);
    }
  }
#pragma unroll
  for (int m = 1; m <= 4; m <<= 1) {
    ss += __shfl_xor(ss, m, 64);
#pragma unroll
    for (int c = 0; c < NCLS; c++) acc[c] += __shfl_xor(acc[c], m, 64);
  }
  int myc = 0, lslot = 0;
  if (part == 0) {
    ((float*)(ws + WS_SQBF))[row] = ss;
    float* proj = (float*)(ws + WS_PROJ);
#pragma unroll
    for (int c = 0; c < NCLS; c++) proj[row * NCLS + c] = acc[c];
    myc = tgt[row];
    lslot = atomicAdd(&lcnt[myc], 1);
  }
  __syncthreads();
  if (t < NCLS) {
    int n = lcnt[t];
    gbase_s[t] = (n > 0) ? atomicAdd((int*)(ws + WS_GCUR + t * 64), n) : 0;
  }
  __syncthreads();
  if (part == 0) {
    ((int*)(ws + WS_PERM))[myc * NROW + gbase_s[myc] + lslot] = row;
  }
}

// ---------------- K2: class-tile x class-tile MFMA + fused epilogue ----------
// grid 42*42, 256 thr (4 waves). Block: A-tile(128 rows, class cA) x
// B-tile(128 rows, class cB); cA==cB blocks exit. wg uniform -> raw sum(M),
// sum(M^2). B-tile in LDS (XOR swizzle). Wave: 32 A-rows, afrag[2][4].
__global__ void __launch_bounds__(256)
k_main(char* __restrict__ ws, float* __restrict__ out) {
  const int t = threadIdx.x;
  int h[NCLS];
#pragma unroll
  for (int c = 0; c < NCLS; c++) h[c] = *((const int*)(ws + WS_GCUR + c * 64));

  int at = blockIdx.x / MAXT, bt = blockIdx.x % MAXT;
  int acc = 0, clsA = 0, ka = 0, clsB = 0, kb = 0;
#pragma unroll
  for (int c = 0; c < NCLS; c++) {
    int tc = (h[c] + 127) >> 7;
    if (at >= acc && at < acc + tc) { clsA = c; ka = at - acc; }
    if (bt >= acc && bt < acc + tc) { clsB = c; kb = bt - acc; }
    acc += tc;
  }
  const int ntiles = acc;
  const bool active = (at < ntiles) && (bt < ntiles) && (clsA != clsB);

  int bias = 0;
  if (active) {
    const int avcnt = min(128, h[clsA] - ka * 128);
    const int bvcnt = min(128, h[clsB] - kb * 128);
    const float wg = (1.0f / (float)h[clsA]) * (1.0f / (float)h[clsB]);
    const float invwn_cls = ((const float*)(ws + WS_INVWN))[clsA];

    __shared__ __align__(16) char Btile[128 * 256];   // 32 KB
    __shared__ __align__(16) float sqa_s[128], pa_s[128];
    __shared__ float sqb_s[128], pnb_s[128];
    __shared__ int   brow_s[128], arow_s[128];
    __shared__ float red_s[4][2];

    const float* sqbf = (const float*)(ws + WS_SQBF);
    const float* proj = (const float*)(ws + WS_PROJ);
    const int*   perm = (const int*)(ws + WS_PERM);
    const unsigned short* predbf = (const unsigned short*)(ws + WS_PREDBF);

    if (t < 128) {                     // b side
      bool valid = t < bvcnt;
      int brow = valid ? perm[clsB * NROW + kb * 128 + t] : 0;
      brow_s[t] = brow;
      sqb_s[t] = valid ? sqbf[brow] + 1e-16f : __builtin_inff();  // pad: M->0
      pnb_s[t] = valid ? proj[brow * NCLS + clsA] * invwn_cls : 0.0f;
    } else {                           // a side
      int i = t - 128;
      bool valid = i < avcnt;
      int arow = valid ? perm[clsA * NROW + ka * 128 + i] : 0;
      arow_s[i] = arow;
      sqa_s[i] = valid ? sqbf[arow] : __builtin_inff();           // pad: M->0
      pa_s[i]  = proj[arow * NCLS + clsA] * invwn_cls;
    }
    __syncthreads();                   // brow_s/arow_s ready

    // B tile -> LDS: slot s holds row r=s>>4, logical chunk (s&15)^(r&15)
#pragma unroll
    for (int it = 0; it < 8; it++) {
      int s = it * 256 + t;
      int r = s >> 4, cc = (s & 15) ^ (r & 15);
      const unsigned short* gp = predbf + brow_s[r] * DDIM + cc * 8;
      __builtin_amdgcn_global_load_lds(AS1(gp), AS3(Btile + s * 16), 16, 0, 0);
    }

    const int lane = t & 63, w = t >> 6;
    const int l16 = lane & 15, quad = lane >> 4;

    // A fragments: wave w covers A-rows [w*32, w*32+32)
    short8 afrag[2][4];
    f32x4 sqa4[2], pa4[2];
#pragma unroll
    for (int fi = 0; fi < 2; fi++) {
      const unsigned short* ap = predbf + arow_s[w * 32 + fi * 16 + l16] * DDIM + quad * 8;
#pragma unroll
      for (int kk = 0; kk < 4; kk++) afrag[fi][kk] = *(const short8*)(ap + kk * 32);
      int m0 = w * 32 + fi * 16 + quad * 4;      // C-layout: row = quad*4 + r
      sqa4[fi] = *(const f32x4*)(sqa_s + m0);
      pa4[fi]  = *(const f32x4*)(pa_s + m0);
    }
    __syncthreads();                   // Btile ready (drains global_load_lds)

    float S1 = 0.f, S2 = 0.f;
#pragma unroll
    for (int s = 0; s < 8; s++) {
      int rb = s * 16 + l16;
      short8 bfrag[4];
#pragma unroll
      for (int kk = 0; kk < 4; kk++)
        bfrag[kk] = *(const short8*)(Btile + rb * 256 + (((quad + kk * 4) ^ l16) * 16));
      float sqb = sqb_s[rb], pnb = pnb_s[rb];
#pragma unroll
      for (int fi = 0; fi < 2; fi++) {
        f32x4 g = {0.f, 0.f, 0.f, 0.f};
#pragma unroll
        for (int kk = 0; kk < 4; kk++)
          g = __builtin_amdgcn_mfma_f32_16x16x32_bf16(afrag[fi][kk], bfrag[kk], g, 0, 0, 0);
#pragma unroll
        for (int r = 0; r < 4; r++) {
          float d2 = fmaf(-2.0f, g[r], sqa4[fi][r] + sqb);   // pads: inf -> rin 0
          float rin = rsqrtf(d2);                            // 1/dn (maxes are no-ops)
          float M = (pa4[fi][r] - pnb) * rin;
          S1 += M;
          S2 = fmaf(M, M, S2);
        }
      }
    }

#pragma unroll
    for (int off = 32; off > 0; off >>= 1) {
      S1 += __shfl_xor(S1, off, 64);
      S2 += __shfl_xor(S2, off, 64);
    }
    if (lane == 0) { red_s[w][0] = S1; red_s[w][1] = S2; }
    __syncthreads();
    if (t == 0) {
      float a1 = (red_s[0][0] + red_s[1][0]) + (red_s[2][0] + red_s[3][0]);
      float a2 = (red_s[0][1] + red_s[1][1]) + (red_s[2][1] + red_s[3][1]);
      float* Sacc = (float*)(ws + WS_SACC);
      float o1 = __hip_atomic_fetch_add(&Sacc[clsA], wg * a1,
                                        __ATOMIC_RELAXED, __HIP_MEMORY_SCOPE_AGENT);
      float o2 = __hip_atomic_fetch_add(&Sacc[10 + clsA], wg * a2,
                                        __ATOMIC_RELAXED, __HIP_MEMORY_SCOPE_AGENT);
      // data dependency: forces wait for the Sacc RMWs before the counter add
      bias = (o1 == -1e30f && o2 == -1e30f) ? 1 : 0;
    }
  }

  // ---- completion counter (no fences); last block finalizes ----
  if (t == 0) {
    int old = __hip_atomic_fetch_add((int*)(ws + WS_DONE), 1 + bias,
                                     __ATOMIC_RELAXED, __HIP_MEMORY_SCOPE_AGENT);
    if (old == GRID_MAIN - 1) {
      float* Sacc = (float*)(ws + WS_SACC);
      float exist = 0.f;
      for (int c = 0; c < NCLS; c++) if (h[c] > 0) exist += 1.f;
      float em1 = exist - 1.0f;        // S0 per class == exist-1 (exact)
      float l1 = 0.f, l2 = 0.f;
      for (int c = 0; c < NCLS; c++) {
        if (h[c] <= 0) continue;
        float s1 = __hip_atomic_load(&Sacc[c],      __ATOMIC_RELAXED, __HIP_MEMORY_SCOPE_AGENT);
        float s2 = __hip_atomic_load(&Sacc[10 + c], __ATOMIC_RELAXED, __HIP_MEMORY_SCOPE_AGENT);
        l1 += (em1 - 2.f * s1 + s2) / em1;
        float mm = s1 / em1;
        float mv = s2 / em1 - mm * mm;
        l2 += fabsf(mv / mm);
      }
      out[0] = l1 / exist;
      out[1] = l2 / exist;
    }
  }
}

extern "C" void kernel_launch(void* const* d_in, const int* in_sizes, int n_in,
                              void* d_out, int out_size, void* d_ws, size_t ws_size,
                              hipStream_t stream) {
  const float* pred = (const float*)d_in[0];
  const int*   tgt  = (const int*)d_in[1];
  const float* W    = (const float*)d_in[2];
  float* out = (float*)d_out;
  char*  ws  = (char*)d_ws;

  hipMemsetAsync(ws, 0, 1024, stream);   // SACC, DONE, GCUR
  k_rows<<<NROW / 32, 256, 0, stream>>>(pred, W, tgt, ws);
  k_main<<<GRID_MAIN, 256, 0, stream>>>(ws, out);
}

// Round 5
// 93.047 us; speedup vs baseline: 1.5680x; 1.2108x over previous
//
#include <hip/hip_runtime.h>

// ---------------- workspace layout (bytes) ----------------
#define WS_GCUR   192      // i32[10], stride 64B (atomic cursors == final counts)
#define WS_INVWN  896      // f32[10]
#define WS_PART   2048     // f32[1764*2] per-block partials (14112 B)
#define WS_SQBF   16384    // f32[4096]
#define WS_PROJ   32768    // f32[4096*10]
#define WS_PERM   196608   // i32[10*4096] fixed 4096-slot region per class (160 KB)
#define WS_PREDBF 360448   // bf16[4096*128] = 1 MB

#define NCLS 10
#define NROW 4096
#define DDIM 128
#define MAXT 42            // max total 128-row class tiles (sum ceil <= 10 + 32)
#define GRID_MAIN (MAXT * MAXT)

typedef __attribute__((ext_vector_type(8))) short short8;
typedef __attribute__((ext_vector_type(4))) float f32x4;

#define AS3(p) ((__attribute__((address_space(3))) void*)(p))
#define AS1(p) ((const __attribute__((address_space(1))) void*)(p))

__device__ __forceinline__ unsigned short f2bf(float x) {
  unsigned int u = __float_as_uint(x);
  u += 0x7FFFu + ((u >> 16) & 1u);   // round-nearest-even
  return (unsigned short)(u >> 16);
}
__device__ __forceinline__ float bf2f(unsigned short b) {
  return __uint_as_float(((unsigned int)b) << 16);
}

// ---------------- K1: bf16 convert, sumsq, proj, invwn, class-sorted perm ----
// 256 blocks x 256 thr; 16 rows/block, 16 threads/row; W in LDS.
__global__ void __launch_bounds__(256)
k_rows(const float* __restrict__ pred, const float* __restrict__ W,
       const int* __restrict__ tgt, char* __restrict__ ws) {
  __shared__ float Wl[NCLS * DDIM];
  __shared__ int lcnt[NCLS];
  __shared__ int gbase_s[NCLS];
  __shared__ int lslot_s[16];
  __shared__ int cls_s[16];
  int t = threadIdx.x;
  if (t < NCLS) lcnt[t] = 0;
  for (int s = t; s < NCLS * DDIM; s += 256) Wl[s] = W[s];
  __syncthreads();

  // ---- perm reservation early (latency overlaps the compute below) ----
  if (t < 16) {
    int myrow = blockIdx.x * 16 + t;
    int c = tgt[myrow];
    cls_s[t] = c;
    lslot_s[t] = atomicAdd(&lcnt[c], 1);
  }
  __syncthreads();
  if (t < NCLS) {
    int n = lcnt[t];
    gbase_s[t] = (n > 0) ? atomicAdd((int*)(ws + WS_GCUR + t * 64), n) : 0;
  }
  // invwn (every block writes the same values; benign)
  if (t >= 64 && t < 224) {
    int i = t - 64;
    int c = i >> 4, ln = i & 15;
    float sw = 0.f;
#pragma unroll
    for (int k = 0; k < 8; k++) { float w = Wl[c * DDIM + ln * 8 + k]; sw = fmaf(w, w, sw); }
    sw += __shfl_xor(sw, 1, 64);
    sw += __shfl_xor(sw, 2, 64);
    sw += __shfl_xor(sw, 4, 64);
    sw += __shfl_xor(sw, 8, 64);
    if (ln == 0) ((float*)(ws + WS_INVWN))[c] = 1.0f / fmaxf(sqrtf(sw), 1e-8f);
  }
  __syncthreads();
  if (t < 16) {
    int c = cls_s[t];
    ((int*)(ws + WS_PERM))[c * NROW + gbase_s[c] + lslot_s[t]] = blockIdx.x * 16 + t;
  }

  // ---- heavy row compute: 16 threads/row, 8 dims each ----
  int row  = blockIdx.x * 16 + (t >> 4);
  int part = t & 15;
  const float4* p4 = (const float4*)(pred + row * DDIM + part * 8);
  unsigned short* pb = ((unsigned short*)(ws + WS_PREDBF)) + row * DDIM + part * 8;

  float4 v[2];
  float ss = 0.f;
#pragma unroll
  for (int ch = 0; ch < 2; ch++) {
    v[ch] = p4[ch];
    unsigned short b0 = f2bf(v[ch].x), b1 = f2bf(v[ch].y),
                   b2 = f2bf(v[ch].z), b3 = f2bf(v[ch].w);
    float r0 = bf2f(b0), r1 = bf2f(b1), r2 = bf2f(b2), r3 = bf2f(b3);
    ss = fmaf(r0, r0, ss); ss = fmaf(r1, r1, ss);
    ss = fmaf(r2, r2, ss); ss = fmaf(r3, r3, ss);
    ushort4 u; u.x = b0; u.y = b1; u.z = b2; u.w = b3;
    *((ushort4*)(pb + ch * 4)) = u;
  }
  float acc[NCLS];
#pragma unroll
  for (int c = 0; c < NCLS; c++) acc[c] = 0.f;
#pragma unroll
  for (int c = 0; c < NCLS; c++) {
#pragma unroll
    for (int ch = 0; ch < 2; ch++) {
      float4 w = *(const float4*)&Wl[c * DDIM + part * 8 + ch * 4];
      acc[c] = fmaf(v[ch].x, w.x, acc[c]);
      acc[c] = fmaf(v[ch].y, w.y, acc[c]);
      acc[c] = fmaf(v[ch].z, w.z, acc[c]);
      acc[c] = fmaf(v[ch].w, w.w, acc[c]);
    }
  }
#pragma unroll
  for (int m = 1; m <= 8; m <<= 1) {
    ss += __shfl_xor(ss, m, 64);
#pragma unroll
    for (int c = 0; c < NCLS; c++) acc[c] += __shfl_xor(acc[c], m, 64);
  }
  if (part == 0) {
    ((float*)(ws + WS_SQBF))[row] = ss;
    float* proj = (float*)(ws + WS_PROJ);
#pragma unroll
    for (int c = 0; c < NCLS; c++) proj[row * NCLS + c] = acc[c];
  }
}

// ---------------- K2: class-tile x class-tile MFMA + fused epilogue ----------
// grid 42*42, 256 thr (4 waves). Block: A-tile(128 rows, class cA) x
// B-tile(128 rows, class cB); cA==cB blocks write zero partials. wg uniform ->
// raw sum(M), sum(M^2) -> unique PART slot. NO global atomics.
__global__ void __launch_bounds__(256)
k_main(char* __restrict__ ws) {
  const int t = threadIdx.x;
  int h[NCLS];
#pragma unroll
  for (int c = 0; c < NCLS; c++) h[c] = *((const int*)(ws + WS_GCUR + c * 64));

  int at = blockIdx.x / MAXT, bt = blockIdx.x % MAXT;
  int acc = 0, clsA = 0, ka = 0, clsB = 0, kb = 0;
#pragma unroll
  for (int c = 0; c < NCLS; c++) {
    int tc = (h[c] + 127) >> 7;
    if (at >= acc && at < acc + tc) { clsA = c; ka = at - acc; }
    if (bt >= acc && bt < acc + tc) { clsB = c; kb = bt - acc; }
    acc += tc;
  }
  const int ntiles = acc;
  const bool active = (at < ntiles) && (bt < ntiles) && (clsA != clsB);

  float p1 = 0.f, p2 = 0.f;
  if (active) {
    const int avcnt = min(128, h[clsA] - ka * 128);
    const int bvcnt = min(128, h[clsB] - kb * 128);
    const float wg = (1.0f / (float)h[clsA]) * (1.0f / (float)h[clsB]);
    const float invwn_cls = ((const float*)(ws + WS_INVWN))[clsA];

    __shared__ __align__(16) char Btile[128 * 256];   // 32 KB
    __shared__ __align__(16) float sqa_s[128], pa_s[128];
    __shared__ float sqb_s[128], pnb_s[128];
    __shared__ int   brow_s[128], arow_s[128];
    __shared__ float red_s[4][2];

    const float* sqbf = (const float*)(ws + WS_SQBF);
    const float* proj = (const float*)(ws + WS_PROJ);
    const int*   perm = (const int*)(ws + WS_PERM);
    const unsigned short* predbf = (const unsigned short*)(ws + WS_PREDBF);

    if (t < 128) {                     // b side
      bool valid = t < bvcnt;
      int brow = valid ? perm[clsB * NROW + kb * 128 + t] : 0;
      brow_s[t] = brow;
      sqb_s[t] = valid ? sqbf[brow] + 1e-16f : __builtin_inff();  // pad: M->0
      pnb_s[t] = valid ? proj[brow * NCLS + clsA] * invwn_cls : 0.0f;
    } else {                           // a side
      int i = t - 128;
      bool valid = i < avcnt;
      int arow = valid ? perm[clsA * NROW + ka * 128 + i] : 0;
      arow_s[i] = arow;
      sqa_s[i] = valid ? sqbf[arow] : __builtin_inff();           // pad: M->0
      pa_s[i]  = proj[arow * NCLS + clsA] * invwn_cls;
    }
    __syncthreads();                   // brow_s/arow_s ready

    // B tile -> LDS: slot s holds row r=s>>4, logical chunk (s&15)^(r&15)
#pragma unroll
    for (int it = 0; it < 8; it++) {
      int s = it * 256 + t;
      int r = s >> 4, cc = (s & 15) ^ (r & 15);
      const unsigned short* gp = predbf + brow_s[r] * DDIM + cc * 8;
      __builtin_amdgcn_global_load_lds(AS1(gp), AS3(Btile + s * 16), 16, 0, 0);
    }

    const int lane = t & 63, w = t >> 6;
    const int l16 = lane & 15, quad = lane >> 4;

    // A fragments: wave w covers A-rows [w*32, w*32+32)
    short8 afrag[2][4];
    f32x4 sqa4[2], pa4[2];
#pragma unroll
    for (int fi = 0; fi < 2; fi++) {
      const unsigned short* ap = predbf + arow_s[w * 32 + fi * 16 + l16] * DDIM + quad * 8;
#pragma unroll
      for (int kk = 0; kk < 4; kk++) afrag[fi][kk] = *(const short8*)(ap + kk * 32);
      int m0 = w * 32 + fi * 16 + quad * 4;      // C-layout: row = quad*4 + r
      sqa4[fi] = *(const f32x4*)(sqa_s + m0);
      pa4[fi]  = *(const f32x4*)(pa_s + m0);
    }
    __syncthreads();                   // Btile ready (drains global_load_lds)

    float S1 = 0.f, S2 = 0.f;
#pragma unroll
    for (int s = 0; s < 8; s++) {
      int rb = s * 16 + l16;
      short8 bfrag[4];
#pragma unroll
      for (int kk = 0; kk < 4; kk++)
        bfrag[kk] = *(const short8*)(Btile + rb * 256 + (((quad + kk * 4) ^ l16) * 16));
      float sqb = sqb_s[rb], pnb = pnb_s[rb];
#pragma unroll
      for (int fi = 0; fi < 2; fi++) {
        f32x4 g = {0.f, 0.f, 0.f, 0.f};
#pragma unroll
        for (int kk = 0; kk < 4; kk++)
          g = __builtin_amdgcn_mfma_f32_16x16x32_bf16(afrag[fi][kk], bfrag[kk], g, 0, 0, 0);
#pragma unroll
        for (int r = 0; r < 4; r++) {
          float d2 = fmaf(-2.0f, g[r], sqa4[fi][r] + sqb);   // pads: inf -> rin 0
          float rin = rsqrtf(d2);                            // 1/dn (maxes are no-ops)
          float M = (pa4[fi][r] - pnb) * rin;
          S1 += M;
          S2 = fmaf(M, M, S2);
        }
      }
    }

#pragma unroll
    for (int off = 32; off > 0; off >>= 1) {
      S1 += __shfl_xor(S1, off, 64);
      S2 += __shfl_xor(S2, off, 64);
    }
    if (lane == 0) { red_s[w][0] = S1; red_s[w][1] = S2; }
    __syncthreads();
    if (t == 0) {
      p1 = wg * ((red_s[0][0] + red_s[1][0]) + (red_s[2][0] + red_s[3][0]));
      p2 = wg * ((red_s[0][1] + red_s[1][1]) + (red_s[2][1] + red_s[3][1]));
    }
  }

  // unique-slot partial write (plain store; kernel boundary publishes it)
  if (t == 0) {
    float* part = (float*)(ws + WS_PART);
    part[blockIdx.x * 2]     = p1;
    part[blockIdx.x * 2 + 1] = p2;
  }
}

// ---------------- K3: reduce partials per class, emit outputs ----------
__global__ void __launch_bounds__(256)
k_final(char* __restrict__ ws, float* __restrict__ out) {
  __shared__ float Sred[2 * NCLS];
  __shared__ int tcls_s[MAXT];
  int t = threadIdx.x;
  if (t < 2 * NCLS) Sred[t] = 0.f;
  __shared__ int h_s[NCLS];
  if (t < NCLS) h_s[t] = *((const int*)(ws + WS_GCUR + t * 64));
  __syncthreads();
  if (t == 0) {
    int nb = 0;
    for (int c = 0; c < NCLS; c++) {
      int tc = (h_s[c] + 127) >> 7;
      for (int i = 0; i < tc && nb + i < MAXT; i++) tcls_s[nb + i] = c;
      nb += tc;
    }
    for (int i = nb; i < MAXT; i++) tcls_s[i] = 0;   // inactive rows wrote zeros
  }
  __syncthreads();
  const float* part = (const float*)(ws + WS_PART);
  for (int i = t; i < GRID_MAIN; i += 256) {
    int c = tcls_s[i / MAXT];
    float v1 = part[i * 2], v2 = part[i * 2 + 1];
    if (v1 != 0.f || v2 != 0.f) {
      atomicAdd(&Sred[c], v1);
      atomicAdd(&Sred[NCLS + c], v2);
    }
  }
  __syncthreads();
  if (t == 0) {
    float exist = 0.f;
    for (int c = 0; c < NCLS; c++) if (h_s[c] > 0) exist += 1.f;
    float em1 = exist - 1.0f;          // S0 per class == exist-1 (exact)
    float l1 = 0.f, l2 = 0.f;
    for (int c = 0; c < NCLS; c++) {
      if (h_s[c] <= 0) continue;
      float s1 = Sred[c], s2 = Sred[NCLS + c];
      l1 += (em1 - 2.f * s1 + s2) / em1;
      float mm = s1 / em1;
      float mv = s2 / em1 - mm * mm;   // (S2 - 2*mm*S1 + mm^2*S0)/em1, S0=em1
      l2 += fabsf(mv / mm);
    }
    out[0] = l1 / exist;
    out[1] = l2 / exist;
  }
}

extern "C" void kernel_launch(void* const* d_in, const int* in_sizes, int n_in,
                              void* d_out, int out_size, void* d_ws, size_t ws_size,
                              hipStream_t stream) {
  const float* pred = (const float*)d_in[0];
  const int*   tgt  = (const int*)d_in[1];
  const float* W    = (const float*)d_in[2];
  float* out = (float*)d_out;
  char*  ws  = (char*)d_ws;

  hipMemsetAsync(ws, 0, 1024, stream);   // zero GCUR (+ header scratch)
  k_rows<<<NROW / 16, 256, 0, stream>>>(pred, W, tgt, ws);
  k_main<<<GRID_MAIN, 256, 0, stream>>>(ws);
  k_final<<<1, 256, 0, stream>>>(ws, out);
}